// Round 10
// baseline (119.800 us; speedup 1.0000x reference)
//
#include <hip/hip_runtime.h>
#include <hip/hip_fp16.h>

// PairwiseMamba: 2304 independent mamba scans (T=1024, d_inner=4, d_state=8).
// R9: barrier-free 2-kernel split. Cross-round finding: total VALU-busy is
// ~30us*SIMD in every config; the loss is busy-fraction (block barriers +
// residency-round quantization). So: K1 has NO __syncthreads and NO combine
// -- every wave-half is an independent uniform job (seq H>>3, segment H&7 of
// 128 steps, 4 chunks), retiring freely -> continuous backfill, no coupled
// stalls. Results {A,hB,W,S} per (half,lane) stream to d_ws (coalesced b128,
// 9.4MB -- WRITE_SIZE grows BY DESIGN, it is not spill; VGPR stays ~50).
// K2 (tiny): per-sequence 8-segment affine prefix + reduce + projection.
// Hot loop = R6's proven body (zero-conflict SoA staging, f16 BC/DS, no
// fences) + pk_fma packed scan state ((A,hB),(W,S) as v2f).

typedef float v2f __attribute__((ext_vector_type(2)));

#define TT 1024
#define TC 32
#define NSEGS 8
#define SEGLEN (TT / NSEGS)            // 128
#define NCHUNK (SEGLEN / TC)           // 4
#define NUM_PAIRS 36
#define NSEQ 2304
#define NHALF (NSEQ * NSEGS)           // 18432 wave-half jobs

// per-(wave,half) staging layout (float/uint slots):
// DT [0,128) floats, DS [128,256) uints, BC [256,520) uints
#define DT_OFF 0
#define DS_OFF 128
#define BC_OFF 256
#define BC_STRIDE 33                   // half2 slots per BC row (bank spread)
#define PER_HALF_STRIDE 528            // floats; %32==16 -> halves bank-disjoint
#define PER_WAVE (2 * PER_HALF_STRIDE) // 1056 floats
#define STAGE_TOTAL (4 * PER_WAVE)     // 4224 floats = 16896 B

__device__ __forceinline__ float fast_silu(float v) {
    float e = __builtin_amdgcn_exp2f(v * -1.4426950408889634f);
    return v * __builtin_amdgcn_rcpf(1.0f + e);
}
// softplus, direct form: log(1+exp(v)). Safe: |v| <~ 20 here.
__device__ __forceinline__ float fast_softplus(float v) {
    float e = __builtin_amdgcn_exp2f(v * 1.4426950408889634f);
    return __builtin_amdgcn_logf(1.0f + e) * 0.6931471805599453f;
}
__device__ __forceinline__ uint pk_h2(float a, float b) {
    return __builtin_bit_cast(uint, __builtin_amdgcn_cvt_pkrtz(a, b));
}

// ---------------- Kernel 1: segment scans (no barriers) ----------------
__global__ __launch_bounds__(256, 4)
void pm_scan(const float* __restrict__ raw,        // (N,2,T)
             const float* __restrict__ in_proj_w,  // (8,2)
             const float* __restrict__ conv_w,     // (4,2)
             const float* __restrict__ conv_b,     // (4)
             const float* __restrict__ x_proj_w,   // (17,4)
             const float* __restrict__ dt_proj_w,  // (4,1)
             const float* __restrict__ dt_proj_b,  // (4)
             const float* __restrict__ A_log,      // (4,8)
             const float* __restrict__ D_skip,     // (4)
             const float* __restrict__ out_proj_w, // (2,4)
             float4* __restrict__ wsA,             // [NHALF*32] {A,hB,W,S}
             float2* __restrict__ wsS)             // [NHALF] skip partials
{
    __shared__ float lds[STAGE_TOTAL];

    const int tid  = threadIdx.x;
    const int wid  = tid >> 6;        // wave 0..3
    const int lane = tid & 63;
    const int half = lane >> 5;
    const int lh   = lane & 31;       // pointwise: t-in-chunk; scan: ds = d*8+s
    const int H    = (blockIdx.x * 4 + wid) * 2 + half;  // flat half-job id
    const int n    = H >> 3;          // sequence
    const int g    = H & 7;           // segment 0..7
    const float* rp = raw + (size_t)n * (2 * TT);

    float* hb = lds + wid * PER_WAVE + half * PER_HALF_STRIDE;

    // ---- weights (wave-uniform -> scalarized) ----
    float ip0[8], ip1[8];
#pragma unroll
    for (int j = 0; j < 8; ++j) { ip0[j] = in_proj_w[2*j]; ip1[j] = in_proj_w[2*j+1]; }
    float dpw[4], dpb[4], Dsk[4], ow0[4], ow1[4], xp0[4];
    v2f alp[2], bep[2], gap[2], dep[2], cbp[2], zc0[2], zc1[2];
#pragma unroll
    for (int d = 0; d < 4; ++d) {
        dpw[d] = dt_proj_w[d]; dpb[d] = dt_proj_b[d];
        Dsk[d] = D_skip[d]; ow0[d] = out_proj_w[d]; ow1[d] = out_proj_w[4+d];
        xp0[d] = x_proj_w[d];
    }
#pragma unroll
    for (int k = 0; k < 2; ++k) {
        int d0 = 2*k, d1 = 2*k + 1;
        float cw00 = conv_w[2*d0], cw01 = conv_w[2*d0+1];
        float cw10 = conv_w[2*d1], cw11 = conv_w[2*d1+1];
        alp[k] = (v2f){cw00*ip0[d0], cw10*ip0[d1]};
        bep[k] = (v2f){cw00*ip1[d0], cw10*ip1[d1]};
        gap[k] = (v2f){cw01*ip0[d0], cw11*ip0[d1]};
        dep[k] = (v2f){cw01*ip1[d0], cw11*ip1[d1]};
        cbp[k] = (v2f){conv_b[d0], conv_b[d1]};
        zc0[k] = (v2f){ip0[4+d0], ip0[4+d1]};
        zc1[k] = (v2f){ip1[4+d0], ip1[4+d1]};
    }
    v2f xbc[8][4];  // {x_proj_w[1+s][d], x_proj_w[9+s][d]}
#pragma unroll
    for (int s = 0; s < 8; ++s)
#pragma unroll
        for (int d = 0; d < 4; ++d)
            xbc[s][d] = (v2f){x_proj_w[4*(1+s) + d], x_proj_w[4*(9+s) + d]};

    const float LOG2E = 1.4426950408889634f;
    const int   d_idx = lh >> 3;
    const int   s_idx = lh & 7;
    const float A2ds  = -__expf(A_log[lh]) * LOG2E;   // a = exp2(dt * A2ds)

    const float* dtp = hb + DT_OFF + d_idx;                  // [t2*4]
    const uint*  dsp = (const uint*)(hb + DS_OFF) + d_idx;   // [t2*4]
    const uint*  bcp = (const uint*)(hb + BC_OFF) + s_idx * BC_STRIDE; // [t2]

    // packed segment-local affine state
    v2f AhB = {1.0f, 0.0f};           // (A_run, hB)
    v2f WS  = {0.0f, 0.0f};           // (W, S)
    float sacc0 = 0.f, sacc1 = 0.f;   // skip-term partials

    const int seg0 = g * SEGLEN;

    int t0 = seg0 + lh;
    float c0  = rp[t0];
    float c1  = rp[TT + t0];
    float c0m = (t0 > 0) ? rp[t0 - 1]      : 0.0f;
    float c1m = (t0 > 0) ? rp[TT + t0 - 1] : 0.0f;

    for (int chunk = 0; chunk < NCHUNK; ++chunk) {
        float p0 = 0.f, p1 = 0.f, p0m = 0.f, p1m = 0.f;
        if (chunk + 1 < NCHUNK) {
            int tn = seg0 + (chunk + 1) * TC + lh;
            p0  = rp[tn];       p1  = rp[TT + tn];
            p0m = rp[tn - 1];   p1m = rp[TT + tn - 1];
        }

        // ---- pointwise: this lane handles t = seg0 + chunk*TC + lh ----
        float x[4], sz[4];
        const v2f c0v = {c0, c0}, c1v = {c1, c1};
        const v2f c0mv = {c0m, c0m}, c1mv = {c1m, c1m};
#pragma unroll
        for (int k = 0; k < 2; ++k) {
            v2f v = __builtin_elementwise_fma(alp[k], c0mv,
                    __builtin_elementwise_fma(bep[k], c1mv,
                    __builtin_elementwise_fma(gap[k], c0v,
                    __builtin_elementwise_fma(dep[k], c1v, cbp[k]))));
            v2f zv = __builtin_elementwise_fma(zc0[k], c0v, zc1[k] * c1v);
            x[2*k]    = fast_silu(v.x);
            x[2*k+1]  = fast_silu(v.y);
            sz[2*k]   = fast_silu(zv.x);
            sz[2*k+1] = fast_silu(zv.y);
        }

        float dtin = xp0[0]*x[0] + xp0[1]*x[1] + xp0[2]*x[2] + xp0[3]*x[3];

        v2f bc[8];
#pragma unroll
        for (int s = 0; s < 8; ++s) {
            v2f a = xbc[s][0] * (v2f){x[0], x[0]};
            a = __builtin_elementwise_fma(xbc[s][1], (v2f){x[1], x[1]}, a);
            a = __builtin_elementwise_fma(xbc[s][2], (v2f){x[2], x[2]}, a);
            bc[s] = __builtin_elementwise_fma(xbc[s][3], (v2f){x[3], x[3]}, a);
        }

        float dt[4];
#pragma unroll
        for (int d = 0; d < 4; ++d) {
            dt[d] = fast_softplus(dtin*dpw[d] + dpb[d]);
            float g2 = x[d] * Dsk[d] * sz[d];
            sacc0 = fmaf(g2, ow0[d], sacc0);
            sacc1 = fmaf(g2, ow1[d], sacc1);
        }

        *(float4*)(hb + DT_OFF + lh*4) = make_float4(dt[0], dt[1], dt[2], dt[3]);
        *(uint4*)((uint*)(hb + DS_OFF) + lh*4) =
            make_uint4(pk_h2(dt[0]*x[0], sz[0]), pk_h2(dt[1]*x[1], sz[1]),
                       pk_h2(dt[2]*x[2], sz[2]), pk_h2(dt[3]*x[3], sz[3]));
        uint* bcw = (uint*)(hb + BC_OFF) + lh;
#pragma unroll
        for (int s = 0; s < 8; ++s)
            bcw[s * BC_STRIDE] = pk_h2(bc[s].x, bc[s].y);

        // ---- scan: lane owns (d_idx, s_idx); packed affine reduction ----
#pragma unroll
        for (int t2 = 0; t2 < TC; ++t2) {
            float dtv = dtp[t2*4];
            uint  uds = dsp[t2*4];
            uint  ubc = bcp[t2];
            __half2 prod = __hmul2(__builtin_bit_cast(__half2, uds),
                                   __builtin_bit_cast(__half2, ubc));
            float b = __half2float(__low2half(prod));       // dtx*B
            float q = __half2float(__high2half(prod));      // sz*C
            float a = __builtin_amdgcn_exp2f(dtv * A2ds);
            AhB = __builtin_elementwise_fma((v2f){a, a}, AhB, (v2f){0.0f, b});
            WS  = __builtin_elementwise_fma(AhB, (v2f){q, q}, WS);
        }

        c0 = p0; c1 = p1; c0m = p0m; c1m = p1m;
    }

    // ---- wave-local epilogue (no barriers) ----
    float s0 = sacc0, s1 = sacc1;
#pragma unroll
    for (int m = 16; m >= 1; m >>= 1) {   // reduce within the 32-lane half
        s0 += __shfl_xor(s0, m, 64);
        s1 += __shfl_xor(s1, m, 64);
    }
    wsA[(size_t)H * 32 + lh] = make_float4(AhB.x, AhB.y, WS.x, WS.y);
    if (lh == 0) wsS[H] = make_float2(s0, s1);
}

// ---------------- Kernel 2: per-sequence combine ----------------
__global__ __launch_bounds__(256, 4)
void pm_comb(const float4* __restrict__ wsA,
             const float2* __restrict__ wsS,
             const float* __restrict__ out_proj_w, // (2,4)
             const float* __restrict__ proj_w,     // (16,2)
             const float* __restrict__ proj_b,     // (16)
             float* __restrict__ out)              // (64,16), pre-zeroed
{
    const int tid  = threadIdx.x;
    const int wid  = tid >> 6;
    const int lane = tid & 63;
    const int half = lane >> 5;
    const int lh   = lane & 31;       // ds = d*8+s
    const int n    = blockIdx.x * 8 + wid * 2 + half;   // sequence, 288 blocks

    const int   d_idx = lh >> 3;
    const float owd0  = out_proj_w[d_idx];
    const float owd1  = out_proj_w[4 + d_idx];

    // sequential affine prefix over the 8 segments
    float h_in = 0.0f, F = 0.0f;
#pragma unroll
    for (int g = 0; g < NSEGS; ++g) {
        float4 v = wsA[(size_t)(n * NSEGS + g) * 32 + lh];  // {A,hB,W,S}
        F    = F + fmaf(h_in, v.z, v.w);
        h_in = fmaf(v.x, h_in, v.y);
    }

    float tot0 = F * owd0;
    float tot1 = F * owd1;
    if (lh < NSEGS) {                  // fold skip partials (one lane per seg)
        float2 sc = wsS[n * NSEGS + lh];
        tot0 += sc.x;
        tot1 += sc.y;
    }
#pragma unroll
    for (int m = 16; m >= 1; m >>= 1) {
        tot0 += __shfl_xor(tot0, m, 64);
        tot1 += __shfl_xor(tot1, m, 64);
    }

    if (lh < 16) {
        float f0 = tot0 * (1.0f / (float)TT);
        float f1 = tot1 * (1.0f / (float)TT);
        float pv = f0*proj_w[2*lh] + f1*proj_w[2*lh + 1] + proj_b[lh];
        pv = fmaxf(pv, 0.0f);
        atomicAdd(out + (n / NUM_PAIRS) * 16 + lh, pv * (1.0f / NUM_PAIRS));
    }
}

extern "C" void kernel_launch(void* const* d_in, const int* in_sizes, int n_in,
                              void* d_out, int out_size, void* d_ws, size_t ws_size,
                              hipStream_t stream)
{
    const float* raw        = (const float*)d_in[0];
    const float* in_proj_w  = (const float*)d_in[1];
    const float* conv_w     = (const float*)d_in[2];
    const float* conv_b     = (const float*)d_in[3];
    const float* x_proj_w   = (const float*)d_in[4];
    const float* dt_proj_w  = (const float*)d_in[5];
    const float* dt_proj_b  = (const float*)d_in[6];
    const float* A_log      = (const float*)d_in[7];
    const float* D_skip     = (const float*)d_in[8];
    const float* out_proj_w = (const float*)d_in[9];
    const float* proj_w     = (const float*)d_in[10];
    const float* proj_b     = (const float*)d_in[11];

    float4* wsA = (float4*)d_ws;                               // 9.44 MB
    float2* wsS = (float2*)((char*)d_ws + (size_t)NHALF * 32 * 16);  // +144 KB

    // d_out is re-poisoned before every timed replay; zero it (atomicAdd sink)
    hipMemsetAsync(d_out, 0, (size_t)out_size * sizeof(float), stream);

    pm_scan<<<dim3(NSEQ), dim3(256), 0, stream>>>(
        raw, in_proj_w, conv_w, conv_b, x_proj_w, dt_proj_w, dt_proj_b,
        A_log, D_skip, out_proj_w, wsA, wsS);

    pm_comb<<<dim3(NSEQ / 8), dim3(256), 0, stream>>>(
        wsA, wsS, out_proj_w, proj_w, proj_b, (float*)d_out);
}